// Round 1
// baseline (1924.622 us; speedup 1.0000x reference)
//
#include <hip/hip_runtime.h>

#define NNODES 100000
#define NEDGES 1000000
#define FIN 64
#define FHID 64
#define FOUT 32

// ---------------------------------------------------------------------------
// Degree count: one atomicAdd per edge into cnt[dst].
__global__ void count_edges(const int* __restrict__ dst, float* __restrict__ cnt) {
    int e = blockIdx.x * blockDim.x + threadIdx.x;
    if (e < NEDGES) atomicAdd(&cnt[dst[e]], 1.0f);
}

// Scatter-add of 64-float rows: 16 threads per edge, float4 per thread.
__global__ void scatter64(const float* __restrict__ x, const int* __restrict__ src,
                          const int* __restrict__ dst, float* __restrict__ msg) {
    int t = blockIdx.x * blockDim.x + threadIdx.x;
    int e = t >> 4;
    if (e >= NEDGES) return;
    int c = (t & 15) << 2;  // feature offset: 0,4,...,60
    int s = src[e], d = dst[e];
    float4 v = *reinterpret_cast<const float4*>(x + (size_t)s * 64 + c);
    float* p = msg + (size_t)d * 64 + c;
    atomicAdd(p + 0, v.x);
    atomicAdd(p + 1, v.y);
    atomicAdd(p + 2, v.z);
    atomicAdd(p + 3, v.w);
}

// ---------------------------------------------------------------------------
// Layer 1: out64 = relu(l2norm(mean @ W1l + b1 + x @ W1r))
// One wave (64 lanes) per node; lane f owns output feature f.
__global__ __launch_bounds__(256) void sage_layer1(
    const float* __restrict__ x, const float* __restrict__ msg,
    const float* __restrict__ cnt, const float* __restrict__ Wl,
    const float* __restrict__ bl, const float* __restrict__ Wr,
    float* __restrict__ h) {
    __shared__ float sWl[64 * 64];
    __shared__ float sWr[64 * 64];
    __shared__ float sb[64];
    __shared__ float sa[4][64];  // mean rows (4 nodes/block)
    __shared__ float sx[4][64];  // x rows
    int tid = threadIdx.x;
    for (int i = tid; i < 64 * 64; i += 256) { sWl[i] = Wl[i]; sWr[i] = Wr[i]; }
    if (tid < 64) sb[tid] = bl[tid];

    int w = tid >> 6;   // local node (wave) index 0..3
    int f = tid & 63;   // output feature = lane
    int node = blockIdx.x * 4 + w;   // NNODES % 4 == 0, always valid
    float c = cnt[node];
    float invc = 1.0f / fmaxf(c, 1.0f);
    sa[w][f] = msg[(size_t)node * 64 + f] * invc;
    sx[w][f] = x[(size_t)node * 64 + f];
    __syncthreads();

    float sum = sb[f];
#pragma unroll
    for (int k = 0; k < 64; ++k) {
        sum = fmaf(sa[w][k], sWl[k * 64 + f], sum);
        sum = fmaf(sx[w][k], sWr[k * 64 + f], sum);
    }
    // row L2 norm across the 64 lanes of this wave
    float sq = sum * sum;
#pragma unroll
    for (int m = 1; m < 64; m <<= 1) sq += __shfl_xor(sq, m, 64);
    float norm = fmaxf(sqrtf(sq), 1e-12f);
    float o = sum / norm;
    h[(size_t)node * 64 + f] = fmaxf(o, 0.0f);  // ReLU
}

// Layer 2: out32 = l2norm(mean @ W2l + b2 + h @ W2r)
// 32 lanes per node, 8 nodes per 256-thread block.
__global__ __launch_bounds__(256) void sage_layer2(
    const float* __restrict__ hbuf, const float* __restrict__ msg,
    const float* __restrict__ cnt, const float* __restrict__ Wl,
    const float* __restrict__ bl, const float* __restrict__ Wr,
    float* __restrict__ out) {
    __shared__ float sWl[64 * 32];
    __shared__ float sWr[64 * 32];
    __shared__ float sb[32];
    __shared__ float sa[8][64];
    __shared__ float sx[8][64];
    int tid = threadIdx.x;
    for (int i = tid; i < 64 * 32; i += 256) { sWl[i] = Wl[i]; sWr[i] = Wr[i]; }
    if (tid < 32) sb[tid] = bl[tid];

    int g = tid >> 5;   // local node 0..7
    int f = tid & 31;   // output feature
    int node = blockIdx.x * 8 + g;   // NNODES % 8 == 0, always valid
    float c = cnt[node];
    float invc = 1.0f / fmaxf(c, 1.0f);
    sa[g][f]      = msg[(size_t)node * 64 + f] * invc;
    sa[g][f + 32] = msg[(size_t)node * 64 + f + 32] * invc;
    sx[g][f]      = hbuf[(size_t)node * 64 + f];
    sx[g][f + 32] = hbuf[(size_t)node * 64 + f + 32];
    __syncthreads();

    float sum = sb[f];
#pragma unroll
    for (int k = 0; k < 64; ++k) {
        sum = fmaf(sa[g][k], sWl[k * 32 + f], sum);
        sum = fmaf(sx[g][k], sWr[k * 32 + f], sum);
    }
    // row L2 norm across this node's 32 lanes (masks <32 stay in-group)
    float sq = sum * sum;
#pragma unroll
    for (int m = 1; m < 32; m <<= 1) sq += __shfl_xor(sq, m, 64);
    float norm = fmaxf(sqrtf(sq), 1e-12f);
    out[(size_t)node * 32 + f] = sum / norm;
}

// ---------------------------------------------------------------------------
extern "C" void kernel_launch(void* const* d_in, const int* in_sizes, int n_in,
                              void* d_out, int out_size, void* d_ws, size_t ws_size,
                              hipStream_t stream) {
    const float* x   = (const float*)d_in[0];
    const int*   ei  = (const int*)d_in[1];      // [2, 1M] row-major (int32)
    const int*   src = ei;                        // edge_index[0]
    const int*   dst = ei + NEDGES;               // edge_index[1]
    const float* W1l = (const float*)d_in[2];
    const float* b1  = (const float*)d_in[3];
    const float* W1r = (const float*)d_in[4];
    const float* W2l = (const float*)d_in[5];
    const float* b2  = (const float*)d_in[6];
    const float* W2r = (const float*)d_in[7];
    float* out = (float*)d_out;

    // workspace layout: msg[N*64] | cnt[N] | h[N*64]  (~51.6 MB)
    float* msg = (float*)d_ws;
    float* cnt = msg + (size_t)NNODES * 64;
    float* h   = cnt + NNODES;

    // zero msg + cnt (contiguous)
    hipMemsetAsync(msg, 0, ((size_t)NNODES * 64 + NNODES) * sizeof(float), stream);

    count_edges<<<(NEDGES + 255) / 256, 256, 0, stream>>>(dst, cnt);
    scatter64<<<(NEDGES * 16) / 256, 256, 0, stream>>>(x, src, dst, msg);
    sage_layer1<<<NNODES / 4, 256, 0, stream>>>(x, msg, cnt, W1l, b1, W1r, h);

    hipMemsetAsync(msg, 0, (size_t)NNODES * 64 * sizeof(float), stream);
    scatter64<<<(NEDGES * 16) / 256, 256, 0, stream>>>(h, src, dst, msg);
    sage_layer2<<<NNODES / 8, 256, 0, stream>>>(h, msg, cnt, W2l, b2, W2r, out);
}

// Round 2
// 417.012 us; speedup vs baseline: 4.6153x; 4.6153x over previous
//
#include <hip/hip_runtime.h>

#define NN 100000
#define NE 1000000
#define NB ((NN + 255) / 256)   // 391 blocks of 256 nodes

// ---------------------------------------------------------------------------
// CSR build: histogram -> two-level exclusive scan -> counting sort of edges.

__global__ void hist_kernel(const int* __restrict__ dst, int* __restrict__ deg) {
    int e = blockIdx.x * blockDim.x + threadIdx.x;
    if (e < NE) atomicAdd(&deg[dst[e]], 1);
}

__global__ void block_sums(const int* __restrict__ deg, int* __restrict__ bsum) {
    __shared__ int s[256];
    int i = blockIdx.x * 256 + threadIdx.x;
    s[threadIdx.x] = (i < NN) ? deg[i] : 0;
    __syncthreads();
    for (int d = 128; d > 0; d >>= 1) {
        if (threadIdx.x < d) s[threadIdx.x] += s[threadIdx.x + d];
        __syncthreads();
    }
    if (threadIdx.x == 0) bsum[blockIdx.x] = s[0];
}

// Exclusive scan of the 391 block sums (single block; serial scan in LDS).
__global__ void scan_bsums(int* __restrict__ bsum, int* __restrict__ off) {
    __shared__ int s[NB];
    int t = threadIdx.x;
    for (int i = t; i < NB; i += blockDim.x) s[i] = bsum[i];
    __syncthreads();
    if (t == 0) {
        int acc = 0;
        for (int i = 0; i < NB; ++i) { int v = s[i]; s[i] = acc; acc += v; }
        off[NN] = acc;  // == NE
    }
    __syncthreads();
    for (int i = t; i < NB; i += blockDim.x) bsum[i] = s[i];
}

// Intra-block Hillis-Steele scan + scanned block offset -> off[], cursor[].
__global__ void write_offsets(const int* __restrict__ deg, const int* __restrict__ bsum,
                              int* __restrict__ off, int* __restrict__ cursor) {
    __shared__ int s[256];
    int t = threadIdx.x;
    int i = blockIdx.x * 256 + t;
    int v = (i < NN) ? deg[i] : 0;
    s[t] = v;
    for (int d = 1; d < 256; d <<= 1) {
        __syncthreads();
        int add = (t >= d) ? s[t - d] : 0;
        __syncthreads();
        s[t] += add;
    }
    __syncthreads();
    if (i < NN) {
        int ex = s[t] - v + bsum[blockIdx.x];   // exclusive prefix
        off[i] = ex;
        cursor[i] = ex;
    }
}

__global__ void scatter_edges(const int* __restrict__ src, const int* __restrict__ dst,
                              int* __restrict__ cursor, int* __restrict__ sorted_src) {
    int e = blockIdx.x * blockDim.x + threadIdx.x;
    if (e < NE) {
        int pos = atomicAdd(&cursor[dst[e]], 1);
        sorted_src[pos] = src[e];
    }
}

// ---------------------------------------------------------------------------
// Layer 1 fused: gather-mean + (mean@Wl + b + x@Wr) + L2norm + ReLU.
// One wave per node, lane f = output feature f. 4 nodes / 256-thread block.
__global__ __launch_bounds__(256) void layer1_fused(
    const float* __restrict__ x, const int* __restrict__ off,
    const int* __restrict__ ssrc, const float* __restrict__ Wl,
    const float* __restrict__ bl, const float* __restrict__ Wr,
    float* __restrict__ h) {
    __shared__ float sWl[64 * 64];
    __shared__ float sWr[64 * 64];
    __shared__ float sb[64];
    __shared__ float sm[4][64];
    __shared__ float sx[4][64];
    int tid = threadIdx.x;
    for (int i = tid; i < 4096; i += 256) { sWl[i] = Wl[i]; sWr[i] = Wr[i]; }
    if (tid < 64) sb[tid] = bl[tid];
    int w = tid >> 6, f = tid & 63;
    int node = blockIdx.x * 4 + w;        // NN % 4 == 0
    int beg = off[node], end = off[node + 1];
    float acc = 0.f;
    int e = beg;
    for (; e + 1 < end; e += 2) {         // unroll 2: overlap gather latency
        int j0 = ssrc[e], j1 = ssrc[e + 1];
        float v0 = x[(size_t)j0 * 64 + f];
        float v1 = x[(size_t)j1 * 64 + f];
        acc += v0; acc += v1;
    }
    if (e < end) acc += x[(size_t)ssrc[e] * 64 + f];
    float invc = 1.0f / fmaxf((float)(end - beg), 1.0f);
    sm[w][f] = acc * invc;
    sx[w][f] = x[(size_t)node * 64 + f];
    __syncthreads();

    float sum = sb[f];
#pragma unroll
    for (int k = 0; k < 64; ++k) {
        sum = fmaf(sm[w][k], sWl[k * 64 + f], sum);   // sm broadcast; sWl 2-way free
        sum = fmaf(sx[w][k], sWr[k * 64 + f], sum);
    }
    float sq = sum * sum;
#pragma unroll
    for (int m = 1; m < 64; m <<= 1) sq += __shfl_xor(sq, m, 64);
    float o = sum / fmaxf(sqrtf(sq), 1e-12f);
    h[(size_t)node * 64 + f] = fmaxf(o, 0.f);         // ReLU
}

// Layer 2 fused: out 32 features. 64 lanes/node: lanes split the k-sum in
// halves (lane f and f^32 each do 32 k's for feature f&31), then shfl-combine.
__global__ __launch_bounds__(256) void layer2_fused(
    const float* __restrict__ hb, const int* __restrict__ off,
    const int* __restrict__ ssrc, const float* __restrict__ Wl,
    const float* __restrict__ bl, const float* __restrict__ Wr,
    float* __restrict__ out) {
    __shared__ float sWl[64 * 32];
    __shared__ float sWr[64 * 32];
    __shared__ float sb[32];
    __shared__ float sm[4][64];
    __shared__ float sx[4][64];
    int tid = threadIdx.x;
    for (int i = tid; i < 2048; i += 256) { sWl[i] = Wl[i]; sWr[i] = Wr[i]; }
    if (tid < 32) sb[tid] = bl[tid];
    int w = tid >> 6, f = tid & 63;
    int node = blockIdx.x * 4 + w;
    int beg = off[node], end = off[node + 1];
    float acc = 0.f;
    int e = beg;
    for (; e + 1 < end; e += 2) {
        int j0 = ssrc[e], j1 = ssrc[e + 1];
        float v0 = hb[(size_t)j0 * 64 + f];
        float v1 = hb[(size_t)j1 * 64 + f];
        acc += v0; acc += v1;
    }
    if (e < end) acc += hb[(size_t)ssrc[e] * 64 + f];
    float invc = 1.0f / fmaxf((float)(end - beg), 1.0f);
    sm[w][f] = acc * invc;
    sx[w][f] = hb[(size_t)node * 64 + f];
    __syncthreads();

    int fo = f & 31;
    int kh = (f >> 5) * 32;
    float sum = (f < 32) ? sb[fo] : 0.f;   // bias counted once after combine
#pragma unroll
    for (int kk = 0; kk < 32; ++kk) {
        int k = kh + kk;
        sum = fmaf(sm[w][k], sWl[k * 32 + fo], sum);
        sum = fmaf(sx[w][k], sWr[k * 32 + fo], sum);
    }
    sum += __shfl_xor(sum, 32, 64);        // combine k-halves
    float sq = sum * sum;
#pragma unroll
    for (int m = 1; m < 32; m <<= 1) sq += __shfl_xor(sq, m, 64);  // 32 feats/half
    if (f < 32) out[(size_t)node * 32 + fo] = sum / fmaxf(sqrtf(sq), 1e-12f);
}

// ---------------------------------------------------------------------------
extern "C" void kernel_launch(void* const* d_in, const int* in_sizes, int n_in,
                              void* d_out, int out_size, void* d_ws, size_t ws_size,
                              hipStream_t stream) {
    const float* x   = (const float*)d_in[0];
    const int*   ei  = (const int*)d_in[1];
    const int*   src = ei;            // edge_index[0]
    const int*   dst = ei + NE;       // edge_index[1]
    const float* W1l = (const float*)d_in[2];
    const float* b1  = (const float*)d_in[3];
    const float* W1r = (const float*)d_in[4];
    const float* W2l = (const float*)d_in[5];
    const float* b2  = (const float*)d_in[6];
    const float* W2r = (const float*)d_in[7];
    float* out = (float*)d_out;

    // ws: deg[N] | bsum[NB] | off[N+1] | cursor[N] | sorted_src[E] | h[N*64]
    int* deg    = (int*)d_ws;
    int* bsum   = deg + NN;
    int* off    = bsum + NB;
    int* cursor = off + NN + 1;
    int* ssrc   = cursor + NN;
    float* h    = (float*)(ssrc + NE);

    hipMemsetAsync(deg, 0, (size_t)NN * sizeof(int), stream);

    hist_kernel  <<<(NE + 255) / 256, 256, 0, stream>>>(dst, deg);
    block_sums   <<<NB, 256, 0, stream>>>(deg, bsum);
    scan_bsums   <<<1, 512, 0, stream>>>(bsum, off);
    write_offsets<<<NB, 256, 0, stream>>>(deg, bsum, off, cursor);
    scatter_edges<<<(NE + 255) / 256, 256, 0, stream>>>(src, dst, cursor, ssrc);

    layer1_fused<<<NN / 4, 256, 0, stream>>>(x, off, ssrc, W1l, b1, W1r, h);
    layer2_fused<<<NN / 4, 256, 0, stream>>>(h, off, ssrc, W2l, b2, W2r, out);
}

// Round 3
// 257.784 us; speedup vs baseline: 7.4660x; 1.6177x over previous
//
#include <hip/hip_runtime.h>

#define NN 100000
#define NE 1000000
#define NB ((NN + 255) / 256)   // 391

typedef __attribute__((ext_vector_type(8))) short bf16x8;
typedef __attribute__((ext_vector_type(4))) float f32x4;

// ---------------------------------------------------------------------------
// bf16 helpers (RNE)
__device__ __forceinline__ ushort f2bf(float f) {
    uint u = __builtin_bit_cast(uint, f);
    u += 0x7FFFu + ((u >> 16) & 1u);
    return (ushort)(u >> 16);
}
__device__ __forceinline__ uint pack2(float a, float b) {
    uint ua = __builtin_bit_cast(uint, a), ub = __builtin_bit_cast(uint, b);
    ua += 0x7FFFu + ((ua >> 16) & 1u);
    ub += 0x7FFFu + ((ub >> 16) & 1u);
    return (ua >> 16) | (ub & 0xFFFF0000u);
}
__device__ __forceinline__ float blo(uint v) { return __builtin_bit_cast(float, v << 16); }
__device__ __forceinline__ float bhi(uint v) { return __builtin_bit_cast(float, v & 0xFFFF0000u); }

// ---------------------------------------------------------------------------
// Prep: x fp32 -> xb bf16 (vectorized), weights -> transposed bf16 [Fout][128]
__global__ void cvt_x(const float* __restrict__ x, uint* __restrict__ xb2) {
    int t = blockIdx.x * blockDim.x + threadIdx.x;   // one float4 per thread
    if (t < NN * 16) {
        float4 v = reinterpret_cast<const float4*>(x)[t];
        uint2 o;
        o.x = pack2(v.x, v.y);
        o.y = pack2(v.z, v.w);
        reinterpret_cast<uint2*>(xb2)[t] = o;
    }
}

// W1t[f][k] (64x128): k<64 -> W1l[k][f], else W1r[k-64][f];  W2t (32x128) same.
__global__ void prep_w(const float* __restrict__ W1l, const float* __restrict__ W1r,
                       const float* __restrict__ W2l, const float* __restrict__ W2r,
                       ushort* __restrict__ W1t, ushort* __restrict__ W2t) {
    int t = blockIdx.x * blockDim.x + threadIdx.x;
    if (t < 64 * 128) {
        int f = t >> 7, k = t & 127;
        float v = (k < 64) ? W1l[k * 64 + f] : W1r[(k - 64) * 64 + f];
        W1t[t] = f2bf(v);
    } else if (t < 64 * 128 + 32 * 128) {
        int u = t - 64 * 128;
        int f = u >> 7, k = u & 127;
        float v = (k < 64) ? W2l[k * 32 + f] : W2r[(k - 64) * 32 + f];
        W2t[u] = f2bf(v);
    }
}

// ---------------------------------------------------------------------------
// CSR build: histogram -> two-level exclusive scan -> counting sort of edges.
__global__ void hist_kernel(const int* __restrict__ dst, int* __restrict__ deg) {
    int e = blockIdx.x * blockDim.x + threadIdx.x;
    if (e < NE) atomicAdd(&deg[dst[e]], 1);
}

__global__ void block_sums(const int* __restrict__ deg, int* __restrict__ bsum) {
    __shared__ int s[256];
    int i = blockIdx.x * 256 + threadIdx.x;
    s[threadIdx.x] = (i < NN) ? deg[i] : 0;
    __syncthreads();
    for (int d = 128; d > 0; d >>= 1) {
        if (threadIdx.x < d) s[threadIdx.x] += s[threadIdx.x + d];
        __syncthreads();
    }
    if (threadIdx.x == 0) bsum[blockIdx.x] = s[0];
}

__global__ void scan_bsums(int* __restrict__ bsum, int* __restrict__ off) {
    __shared__ int s[NB];
    int t = threadIdx.x;
    for (int i = t; i < NB; i += blockDim.x) s[i] = bsum[i];
    __syncthreads();
    if (t == 0) {
        int acc = 0;
        for (int i = 0; i < NB; ++i) { int v = s[i]; s[i] = acc; acc += v; }
        off[NN] = acc;  // == NE
    }
    __syncthreads();
    for (int i = t; i < NB; i += blockDim.x) bsum[i] = s[i];
}

__global__ void write_offsets(const int* __restrict__ deg, const int* __restrict__ bsum,
                              int* __restrict__ off, int* __restrict__ cursor) {
    __shared__ int s[256];
    int t = threadIdx.x;
    int i = blockIdx.x * 256 + t;
    int v = (i < NN) ? deg[i] : 0;
    s[t] = v;
    for (int d = 1; d < 256; d <<= 1) {
        __syncthreads();
        int add = (t >= d) ? s[t - d] : 0;
        __syncthreads();
        s[t] += add;
    }
    __syncthreads();
    if (i < NN) {
        int ex = s[t] - v + bsum[blockIdx.x];
        off[i] = ex;
        cursor[i] = ex;
    }
}

__global__ void scatter_edges(const int* __restrict__ src, const int* __restrict__ dst,
                              int* __restrict__ cursor, int* __restrict__ sorted_src) {
    int e = blockIdx.x * blockDim.x + threadIdx.x;
    if (e < NE) {
        int pos = atomicAdd(&cursor[dst[e]], 1);
        sorted_src[pos] = src[e];
    }
}

// ---------------------------------------------------------------------------
// Gather-mean over bf16 rows (64 feats = 32 uints). One wave per node; the two
// 32-lane halves take alternating edges (2 rows in flight each, unroll 2).
__global__ __launch_bounds__(256) void gmean(const uint* __restrict__ xb2,
                                             const int* __restrict__ off,
                                             const int* __restrict__ ssrc,
                                             uint* __restrict__ mb2) {
    int l = threadIdx.x & 63;
    int node = blockIdx.x * 4 + (threadIdx.x >> 6);   // NN % 4 == 0
    int half = l >> 5, c = l & 31;
    int beg = off[node], end = off[node + 1];
    float a0 = 0.f, a1 = 0.f;
    int i = beg + half;
    for (; i + 2 < end; i += 4) {
        int j0 = ssrc[i], j1 = ssrc[i + 2];
        uint v0 = xb2[(size_t)j0 * 32 + c];
        uint v1 = xb2[(size_t)j1 * 32 + c];
        a0 += blo(v0); a1 += bhi(v0);
        a0 += blo(v1); a1 += bhi(v1);
    }
    if (i < end) {
        uint v = xb2[(size_t)ssrc[i] * 32 + c];
        a0 += blo(v); a1 += bhi(v);
    }
    a0 += __shfl_xor(a0, 32, 64);
    a1 += __shfl_xor(a1, 32, 64);
    if (half == 0) {
        float invc = 1.f / fmaxf((float)(end - beg), 1.f);
        mb2[(size_t)node * 32 + c] = pack2(a0 * invc, a1 * invc);
    }
}

// ---------------------------------------------------------------------------
// Layer 1 MFMA: hb = relu(l2norm([mean|x] @ W1t^T + b1)), bf16 out.
// Wave = 16 nodes x 64 feats; 4 waves/block = 64 nodes. K=128 in 4 MFMA steps,
// 4 column tiles. A m-index = lane&15; B n-index = lane&15; both use the same
// contiguous-8 k-chunk assignment (result invariant to HW k-permutation).
// C layout: col = lane&15, row = (lane>>4)*4 + reg  [m89-verified].
__global__ __launch_bounds__(256) void layer1_mfma(
    const ushort* __restrict__ mb, const ushort* __restrict__ xb,
    const ushort* __restrict__ Wt, const float* __restrict__ bias,
    ushort* __restrict__ hb) {
    int w = threadIdx.x >> 6, l = threadIdx.x & 63;
    int r = l & 15, q = l >> 4;
    int node0 = blockIdx.x * 64 + w * 16;
    int arow = node0 + r;
    if (arow >= NN) arow = NN - 1;      // clamp; invalid rows never stored
    const ushort* am = mb + (size_t)arow * 64 + q * 8;
    const ushort* ax = xb + (size_t)arow * 64 + q * 8;
    bf16x8 afr[4];
    afr[0] = *reinterpret_cast<const bf16x8*>(am);
    afr[1] = *reinterpret_cast<const bf16x8*>(am + 32);
    afr[2] = *reinterpret_cast<const bf16x8*>(ax);
    afr[3] = *reinterpret_cast<const bf16x8*>(ax + 32);

    f32x4 c0 = {0.f, 0.f, 0.f, 0.f}, c1 = c0, c2 = c0, c3 = c0;
    const ushort* wp = Wt + (size_t)r * 128 + q * 8;
#pragma unroll
    for (int ks = 0; ks < 4; ++ks) {
        const ushort* wk = wp + ks * 32;
        bf16x8 b0 = *reinterpret_cast<const bf16x8*>(wk);
        bf16x8 b1 = *reinterpret_cast<const bf16x8*>(wk + 16 * 128);
        bf16x8 b2 = *reinterpret_cast<const bf16x8*>(wk + 32 * 128);
        bf16x8 b3 = *reinterpret_cast<const bf16x8*>(wk + 48 * 128);
        c0 = __builtin_amdgcn_mfma_f32_16x16x32_bf16(afr[ks], b0, c0, 0, 0, 0);
        c1 = __builtin_amdgcn_mfma_f32_16x16x32_bf16(afr[ks], b1, c1, 0, 0, 0);
        c2 = __builtin_amdgcn_mfma_f32_16x16x32_bf16(afr[ks], b2, c2, 0, 0, 0);
        c3 = __builtin_amdgcn_mfma_f32_16x16x32_bf16(afr[ks], b3, c3, 0, 0, 0);
    }
    float bb0 = bias[r], bb1 = bias[16 + r], bb2 = bias[32 + r], bb3 = bias[48 + r];
#pragma unroll
    for (int reg = 0; reg < 4; ++reg) {
        c0[reg] += bb0; c1[reg] += bb1; c2[reg] += bb2; c3[reg] += bb3;
    }
    float sc[4];
#pragma unroll
    for (int reg = 0; reg < 4; ++reg) {
        float s = c0[reg] * c0[reg] + c1[reg] * c1[reg] +
                  c2[reg] * c2[reg] + c3[reg] * c3[reg];
        s += __shfl_xor(s, 1, 64);
        s += __shfl_xor(s, 2, 64);
        s += __shfl_xor(s, 4, 64);
        s += __shfl_xor(s, 8, 64);
        sc[reg] = 1.f / fmaxf(sqrtf(s), 1e-12f);
    }
#pragma unroll
    for (int reg = 0; reg < 4; ++reg) {
        int grow = node0 + q * 4 + reg;
        if (grow < NN) {
            ushort* hp = hb + (size_t)grow * 64 + r;
            hp[0]  = f2bf(fmaxf(c0[reg] * sc[reg], 0.f));
            hp[16] = f2bf(fmaxf(c1[reg] * sc[reg], 0.f));
            hp[32] = f2bf(fmaxf(c2[reg] * sc[reg], 0.f));
            hp[48] = f2bf(fmaxf(c3[reg] * sc[reg], 0.f));
        }
    }
}

// Layer 2 MFMA: out = l2norm([mean2|h] @ W2t^T + b2), fp32 out, 32 feats.
__global__ __launch_bounds__(256) void layer2_mfma(
    const ushort* __restrict__ mb, const ushort* __restrict__ hbuf,
    const ushort* __restrict__ Wt, const float* __restrict__ bias,
    float* __restrict__ out) {
    int w = threadIdx.x >> 6, l = threadIdx.x & 63;
    int r = l & 15, q = l >> 4;
    int node0 = blockIdx.x * 64 + w * 16;
    int arow = node0 + r;
    if (arow >= NN) arow = NN - 1;
    const ushort* am = mb + (size_t)arow * 64 + q * 8;
    const ushort* ax = hbuf + (size_t)arow * 64 + q * 8;
    bf16x8 afr[4];
    afr[0] = *reinterpret_cast<const bf16x8*>(am);
    afr[1] = *reinterpret_cast<const bf16x8*>(am + 32);
    afr[2] = *reinterpret_cast<const bf16x8*>(ax);
    afr[3] = *reinterpret_cast<const bf16x8*>(ax + 32);

    f32x4 c0 = {0.f, 0.f, 0.f, 0.f}, c1 = c0;
    const ushort* wp = Wt + (size_t)r * 128 + q * 8;
#pragma unroll
    for (int ks = 0; ks < 4; ++ks) {
        const ushort* wk = wp + ks * 32;
        bf16x8 b0 = *reinterpret_cast<const bf16x8*>(wk);
        bf16x8 b1 = *reinterpret_cast<const bf16x8*>(wk + 16 * 128);
        c0 = __builtin_amdgcn_mfma_f32_16x16x32_bf16(afr[ks], b0, c0, 0, 0, 0);
        c1 = __builtin_amdgcn_mfma_f32_16x16x32_bf16(afr[ks], b1, c1, 0, 0, 0);
    }
    float bb0 = bias[r], bb1 = bias[16 + r];
#pragma unroll
    for (int reg = 0; reg < 4; ++reg) { c0[reg] += bb0; c1[reg] += bb1; }
    float sc[4];
#pragma unroll
    for (int reg = 0; reg < 4; ++reg) {
        float s = c0[reg] * c0[reg] + c1[reg] * c1[reg];
        s += __shfl_xor(s, 1, 64);
        s += __shfl_xor(s, 2, 64);
        s += __shfl_xor(s, 4, 64);
        s += __shfl_xor(s, 8, 64);
        sc[reg] = 1.f / fmaxf(sqrtf(s), 1e-12f);
    }
#pragma unroll
    for (int reg = 0; reg < 4; ++reg) {
        int grow = node0 + q * 4 + reg;
        if (grow < NN) {
            float* op = out + (size_t)grow * 32 + r;
            op[0]  = c0[reg] * sc[reg];
            op[16] = c1[reg] * sc[reg];
        }
    }
}

// ---------------------------------------------------------------------------
extern "C" void kernel_launch(void* const* d_in, const int* in_sizes, int n_in,
                              void* d_out, int out_size, void* d_ws, size_t ws_size,
                              hipStream_t stream) {
    const float* x   = (const float*)d_in[0];
    const int*   ei  = (const int*)d_in[1];
    const int*   src = ei;            // edge_index[0]
    const int*   dst = ei + NE;       // edge_index[1]
    const float* W1l = (const float*)d_in[2];
    const float* b1  = (const float*)d_in[3];
    const float* W1r = (const float*)d_in[4];
    const float* W2l = (const float*)d_in[5];
    const float* b2  = (const float*)d_in[6];
    const float* W2r = (const float*)d_in[7];
    float* out = (float*)d_out;

    // ws: xb[N*64]b16 | mb[N*64]b16 | hb[N*64]b16 | W1t[64*128]b16 | W2t[32*128]b16
    //     | deg[N] | bsum[NB] | off[N+1] | cursor[N] | ssrc[E]     (~43.6 MB)
    ushort* xb  = (ushort*)d_ws;
    ushort* mb  = xb + (size_t)NN * 64;
    ushort* hb  = mb + (size_t)NN * 64;
    ushort* W1t = hb + (size_t)NN * 64;
    ushort* W2t = W1t + 64 * 128;
    int* deg    = (int*)(W2t + 32 * 128);
    int* bsum   = deg + NN;
    int* off    = bsum + NB;
    int* cursor = off + NN + 1;
    int* ssrc   = cursor + NN;

    hipMemsetAsync(deg, 0, (size_t)NN * sizeof(int), stream);

    cvt_x        <<<(NN * 16 + 255) / 256, 256, 0, stream>>>(x, (uint*)xb);
    prep_w       <<<48, 256, 0, stream>>>(W1l, W1r, W2l, W2r, W1t, W2t);
    hist_kernel  <<<(NE + 255) / 256, 256, 0, stream>>>(dst, deg);
    block_sums   <<<NB, 256, 0, stream>>>(deg, bsum);
    scan_bsums   <<<1, 512, 0, stream>>>(bsum, off);
    write_offsets<<<NB, 256, 0, stream>>>(deg, bsum, off, cursor);
    scatter_edges<<<(NE + 255) / 256, 256, 0, stream>>>(src, dst, cursor, ssrc);

    gmean      <<<NN / 4, 256, 0, stream>>>((const uint*)xb, off, ssrc, (uint*)mb);
    layer1_mfma<<<(NN + 63) / 64, 256, 0, stream>>>(mb, xb, W1t, b1, hb);
    gmean      <<<NN / 4, 256, 0, stream>>>((const uint*)hb, off, ssrc, (uint*)mb);
    layer2_mfma<<<(NN + 63) / 64, 256, 0, stream>>>(mb, hb, W2t, b2, out);
}